// Round 12
// baseline (355.539 us; speedup 1.0000x reference)
//
#include <hip/hip_runtime.h>
#include <math.h>

#define LSZ 128
#define NCH 8
#define NLAY 16
#define LOG2E 1.4426950408889634f
#define LN2   0.6931471805599453f

typedef float f4 __attribute__((ext_vector_type(4)));
typedef float f2 __attribute__((ext_vector_type(2)));

// wave-uniform float -> SGPR
__device__ __forceinline__ float uni(float v) {
    return __uint_as_float(__builtin_amdgcn_readfirstlane(__float_as_uint(v)));
}

// unpack 2 bf16 from u32 (bf16->f32 exact)
__device__ __forceinline__ f2 unpk2(unsigned u) {
    f2 r;
    r.x = __uint_as_float(u << 16);
    r.y = __uint_as_float(u & 0xffff0000u);
    return r;
}
struct f8 { f4 a, b; };
// read 8 bf16 (one ds_read_b128) -> two f4
__device__ __forceinline__ f8 ldr8(const unsigned short* p) {
    uint4 w = *(const uint4*)p;
    f2 p0 = unpk2(w.x), p1 = unpk2(w.y), p2 = unpk2(w.z), p3 = unpk2(w.w);
    f8 r;
    r.a = (f4){p0.x, p0.y, p1.x, p1.y};
    r.b = (f4){p2.x, p2.y, p3.x, p3.y};
    return r;
}
// read 4 bf16 (one ds_read_b64) -> f4
__device__ __forceinline__ f4 ldr4(const unsigned short* p) {
    uint2 w = *(const uint2*)p;
    f2 p0 = unpk2(w.x), p1 = unpk2(w.y);
    return (f4){p0.x, p0.y, p1.x, p1.y};
}
// pack 8 f32 -> 8 bf16 RNE (v_cvt_pk_bf16_f32), one ds_write_b128
__device__ __forceinline__ void str8(unsigned short* p, f4 va, f4 vb) {
    unsigned q0, q1, q2, q3;
    asm("v_cvt_pk_bf16_f32 %0, %1, %2" : "=v"(q0) : "v"(va.x), "v"(va.y));
    asm("v_cvt_pk_bf16_f32 %0, %1, %2" : "=v"(q1) : "v"(va.z), "v"(va.w));
    asm("v_cvt_pk_bf16_f32 %0, %1, %2" : "=v"(q2) : "v"(vb.x), "v"(vb.y));
    asm("v_cvt_pk_bf16_f32 %0, %1, %2" : "=v"(q3) : "v"(vb.z), "v"(vb.w));
    *(uint4*)p = make_uint4(q0, q1, q2, q3);
}

// One block per (batch, channel) plane. 512 threads: 32 row-strips x 16
// col-groups, each thread 4 rows x 8 cols. BF16 ping-pong planes (32 KB each),
// single barrier per layer. All tile state re-read from LDS each layer
// (halo rows AND own rows) -> small register bank, wide b128 row reads.
// Uniform-shift fold: x = x~ - l; weights pre-scaled by log2e;
// CELU tail = fma(max(y',0), ln2, x~) + exp2(min(y',0)).
__global__ __launch_bounds__(512)
void plane_kernel(const float* __restrict__ nrm,   // (256,128,3)
                  const float* __restrict__ W,     // (16,8,5)
                  float* __restrict__ ws)          // (2048,) per-block sums
{
    __shared__ __align__(16) unsigned short xa[LSZ * LSZ];   // 32768 B
    __shared__ __align__(16) unsigned short xb[LSZ * LSZ];   // 32768 B
    __shared__ float nsm[LSZ * 3];
    __shared__ float wsm[NLAY * 5];
    __shared__ float red[8];

    const int bid = blockIdx.x;
    const int b   = bid >> 3;
    const int c   = bid & 7;
    const int tid = threadIdx.x;

    if (tid < LSZ * 3) nsm[tid] = nrm[b * (LSZ * 3) + tid];
    if (tid < NLAY * 5) {
        int l = tid / 5, d = tid % 5;
        wsm[tid] = W[l * (NCH * 5) + c * 5 + d] * LOG2E;   // pre-scaled
    }
    __syncthreads();

    const int jg = tid & 15;        // col group  -> j0 = 8*jg
    const int is = tid >> 4;        // row strip  -> i0 = 4*is
    const int j0 = jg * 8;
    const int i0 = is * 4;

    // ---- init: g[i][j] = dot3(n[i], n[j]), zero diagonal ----
    {
        float njx[8], njy[8], njz[8];
#pragma unroll
        for (int q = 0; q < 8; ++q) {
            njx[q] = nsm[(j0 + q) * 3 + 0];
            njy[q] = nsm[(j0 + q) * 3 + 1];
            njz[q] = nsm[(j0 + q) * 3 + 2];
        }
#pragma unroll
        for (int k = 0; k < 4; ++k) {
            int r = i0 + k;
            float n0 = nsm[r * 3 + 0], n1 = nsm[r * 3 + 1], n2 = nsm[r * 3 + 2];
            float g[8];
#pragma unroll
            for (int q = 0; q < 8; ++q) {
                g[q] = n0 * njx[q] + n1 * njy[q] + n2 * njz[q];
                if (r == j0 + q) g[q] = 0.f;
            }
            str8(&xa[r * LSZ + j0], (f4){g[0], g[1], g[2], g[3]},
                                    (f4){g[4], g[5], g[6], g[7]});
        }
    }
    __syncthreads();

    // LDS offsets (bf16 elements). Halo strips 4-row-aligned -> contiguous
    // across the wrap; row offsets k*LSZ become ds immediates.
    const int oT = ((i0 - 4) & (LSZ - 1)) * LSZ + j0;   // top halo rows
    const int oB = ((i0 + 4) & (LSZ - 1)) * LSZ + j0;   // bottom halo rows
    const int oL = i0 * LSZ + ((j0 - 4) & (LSZ - 1));   // left 4 cols
    const int oR = i0 * LSZ + ((j0 + 8) & (LSZ - 1));   // right 4 cols
    const int oO = i0 * LSZ + j0;                       // own rows

    float lsum = 0.f;   // final-layer partial sum (accumulated inline)

    auto do_layer = [&](const unsigned short* src, unsigned short* dst, int l) {
        const float w0 = uni(wsm[l * 5 + 0]);
        const float w1 = uni(wsm[l * 5 + 1]);
        const float w2 = uni(wsm[l * 5 + 2]);
        const float w3 = uni(wsm[l * 5 + 3]);
        const float w4 = uni(wsm[l * 5 + 4]);
        // uniform shift: entering layer l, x = x~ - l; stencil(const) = s*T
        const float sT = -(float)l * (w0 + 4.0f * (w1 + w2 + w3 + w4));

        f4 ta[4], tb[4], oa[4], ob[4], ba[4], bb[4];
#pragma unroll
        for (int k = 0; k < 4; ++k) {
            f8 r;
            r = ldr8(&src[oT + k * LSZ]); ta[k] = r.a; tb[k] = r.b;
            r = ldr8(&src[oO + k * LSZ]); oa[k] = r.a; ob[k] = r.b;
            r = ldr8(&src[oB + k * LSZ]); ba[k] = r.a; bb[k] = r.b;
        }

        // VA/VB(k): vertical stack rows i0-4+k, k=0..11 (a/b = col halves)
#define VA(k) ((k) < 4 ? ta[(k)] : (k) < 8 ? oa[(k) - 4] : ba[(k) - 8])
#define VB(k) ((k) < 4 ? tb[(k)] : (k) < 8 ? ob[(k) - 4] : bb[(k) - 8])

#pragma unroll
        for (int m = 0; m < 4; ++m) {
            const f4 A = ldr4(&src[oL + m * LSZ]);   // cols j0-4..j0-1
            const f4 D = ldr4(&src[oR + m * LSZ]);   // cols j0+8..j0+11
            const f4 B = oa[m], C = ob[m];

            // horizontal shifted-pair taps (pk-pair structured)
            f4 h1a; { f2 t = B.xy + B.zw; h1a = (f4){A.w + B.y, t.x, t.y, B.z + C.x}; }
            f4 h2a; { f2 u = A.zw + B.zw; f2 v = B.xy + C.xy; h2a = (f4){u.x, u.y, v.x, v.y}; }
            f4 h3a; { f2 t = A.zw + C.xy; h3a = (f4){A.y + B.w, t.x, t.y, B.x + C.z}; }
            f4 h4a = A + C;
            f4 h1b; { f2 t = C.xy + C.zw; h1b = (f4){B.w + C.y, t.x, t.y, C.z + D.x}; }
            f4 h2b; { f2 u = B.zw + C.zw; f2 v = C.xy + D.xy; h2b = (f4){u.x, u.y, v.x, v.y}; }
            f4 h3b; { f2 t = B.zw + D.xy; h3b = (f4){B.y + C.w, t.x, t.y, C.x + D.z}; }
            f4 h4b = B + D;

            // y' = y * log2e (weights pre-scaled); sT folded in
            f4 ya = (w0 * B + sT)
                  + w1 * (h1a + (VA(m + 3) + VA(m + 5)))
                  + w2 * (h2a + (VA(m + 2) + VA(m + 6)))
                  + w3 * (h3a + (VA(m + 1) + VA(m + 7)))
                  + w4 * (h4a + (VA(m + 0) + VA(m + 8)));
            f4 yb = (w0 * C + sT)
                  + w1 * (h1b + (VB(m + 3) + VB(m + 5)))
                  + w2 * (h2b + (VB(m + 2) + VB(m + 6)))
                  + w3 * (h3b + (VB(m + 1) + VB(m + 7)))
                  + w4 * (h4b + (VB(m + 0) + VB(m + 8)));

            f4 ypa = __builtin_elementwise_max(ya, (f4)0.0f);
            f4 yna = __builtin_elementwise_min(ya, (f4)0.0f);
            f4 ypb = __builtin_elementwise_max(yb, (f4)0.0f);
            f4 ynb = __builtin_elementwise_min(yb, (f4)0.0f);
            f4 ea, eb;
            ea.x = __builtin_amdgcn_exp2f(yna.x);
            ea.y = __builtin_amdgcn_exp2f(yna.y);
            ea.z = __builtin_amdgcn_exp2f(yna.z);
            ea.w = __builtin_amdgcn_exp2f(yna.w);
            eb.x = __builtin_amdgcn_exp2f(ynb.x);
            eb.y = __builtin_amdgcn_exp2f(ynb.y);
            eb.z = __builtin_amdgcn_exp2f(ynb.z);
            eb.w = __builtin_amdgcn_exp2f(ynb.w);
            f4 ra = (ypa * LN2 + B) + ea;   // x~_next ("-1" lives in shift)
            f4 rb = (ypb * LN2 + C) + eb;

            str8(&dst[oO + m * LSZ], ra, rb);
            if (l == NLAY - 1) {
                f4 s = ra + rb;
                lsum += (s.x + s.y) + (s.z + s.w);
            }
        }
#undef VA
#undef VB
        __syncthreads();                   // single barrier per layer
    };

#pragma unroll 1
    for (int l = 0; l < NLAY; l += 2) {
        do_layer(xa, xb, l);
        do_layer(xb, xa, l + 1);
    }

    // ---- block reduction of last-layer sums ----
    float local = lsum;
#pragma unroll
    for (int off = 32; off > 0; off >>= 1)
        local += __shfl_down(local, off, 64);

    const int wave = tid >> 6;
    if ((tid & 63) == 0) red[wave] = local;
    __syncthreads();
    if (tid == 0) {
        float s = 0.f;
#pragma unroll
        for (int w = 0; w < 8; ++w) s += red[w];
        ws[bid] = s;
    }
}

__global__ void finish_kernel(const float* __restrict__ ws, float* __restrict__ out) {
    int b = threadIdx.x;
    float s = 0.f;
#pragma unroll
    for (int c = 0; c < NCH; ++c) s += ws[b * NCH + c];
    // x = x~ - 16 after all layers: mean_true = mean(x~) - 16
    out[b] = expf(16.0f - s / (8.0f * 128.0f * 128.0f));
}

extern "C" void kernel_launch(void* const* d_in, const int* in_sizes, int n_in,
                              void* d_out, int out_size, void* d_ws, size_t ws_size,
                              hipStream_t stream) {
    const float* nrm = (const float*)d_in[0];   // (256,128,3) f32
    const float* W   = (const float*)d_in[1];   // (16,8,5) f32
    float* out = (float*)d_out;                 // (256,) f32
    float* ws  = (float*)d_ws;                  // >= 2048 f32 scratch

    plane_kernel<<<dim3(256 * NCH), dim3(512), 0, stream>>>(nrm, W, ws);
    finish_kernel<<<dim3(1), dim3(256), 0, stream>>>(ws, out);
}

// Round 13
// 318.489 us; speedup vs baseline: 1.1163x; 1.1163x over previous
//
#include <hip/hip_runtime.h>
#include <math.h>

#define LSZ 128
#define NCH 8
#define NLAY 16
#define LOG2E 1.4426950408889634f
#define LN2   0.6931471805599453f

typedef float f4 __attribute__((ext_vector_type(4)));
typedef float f2 __attribute__((ext_vector_type(2)));

// wave-uniform float -> SGPR
__device__ __forceinline__ float uni(float v) {
    return __uint_as_float(__builtin_amdgcn_readfirstlane(__float_as_uint(v)));
}

// One block per (batch, channel) plane. 1024 threads: 32 row-strips x 32
// col-groups, 4 rows x 4 cols per thread. SINGLE f32 plane in LDS (64 KB),
// updated in place with a compute/stash -> barrier -> write -> barrier
// cycle. Results are stashed into the top-halo registers t[m], which die
// exactly after output row m is computed -> no extra VGPRs vs R10.
// LDS/block ~68 KB -> TWO 1024-thread blocks resident per CU (32 waves):
// cross-block overlap breaks the one-block barrier convoy that R10 showed.
// Uniform-shift fold: x = x~ - l; weights pre-scaled by log2e;
// CELU tail = fma(max(y',0), ln2, x~) + exp2(min(y',0)).
__global__ __launch_bounds__(1024)
void plane_kernel(const float* __restrict__ nrm,   // (256,128,3)
                  const float* __restrict__ W,     // (16,8,5)
                  float* __restrict__ ws)          // (2048,) per-block sums
{
    __shared__ float x[LSZ * LSZ];     // 65536 B
    __shared__ float nsm[LSZ * 3];
    __shared__ float wsm[NLAY * 5];
    __shared__ float red[16];

    const int bid = blockIdx.x;
    const int b   = bid >> 3;
    const int c   = bid & 7;
    const int tid = threadIdx.x;

    if (tid < LSZ * 3) nsm[tid] = nrm[b * (LSZ * 3) + tid];
    if (tid < NLAY * 5) {
        int l = tid / 5, d = tid % 5;
        wsm[tid] = W[l * (NCH * 5) + c * 5 + d] * LOG2E;   // pre-scaled
    }
    __syncthreads();

    const int jg = tid & 31;        // col group  -> j0 = 4*jg
    const int is = tid >> 5;        // row strip  -> i0 = 4*is
    const int j0 = jg * 4;
    const int i0 = is * 4;

    f4 own[4];   // this thread's 4 rows (x~ state, f32, carried in registers)

    // ---- init: g[i][j] = dot3(n[i], n[j]), zero diagonal ----
    {
        float nj0x = nsm[(j0 + 0) * 3 + 0], nj0y = nsm[(j0 + 0) * 3 + 1], nj0z = nsm[(j0 + 0) * 3 + 2];
        float nj1x = nsm[(j0 + 1) * 3 + 0], nj1y = nsm[(j0 + 1) * 3 + 1], nj1z = nsm[(j0 + 1) * 3 + 2];
        float nj2x = nsm[(j0 + 2) * 3 + 0], nj2y = nsm[(j0 + 2) * 3 + 1], nj2z = nsm[(j0 + 2) * 3 + 2];
        float nj3x = nsm[(j0 + 3) * 3 + 0], nj3y = nsm[(j0 + 3) * 3 + 1], nj3z = nsm[(j0 + 3) * 3 + 2];
#pragma unroll
        for (int k = 0; k < 4; ++k) {
            int r = i0 + k;
            float n0 = nsm[r * 3 + 0], n1 = nsm[r * 3 + 1], n2 = nsm[r * 3 + 2];
            float g0 = n0 * nj0x + n1 * nj0y + n2 * nj0z;
            float g1 = n0 * nj1x + n1 * nj1y + n2 * nj1z;
            float g2 = n0 * nj2x + n1 * nj2y + n2 * nj2z;
            float g3 = n0 * nj3x + n1 * nj3y + n2 * nj3z;
            if (r == j0 + 0) g0 = 0.f;
            if (r == j0 + 1) g1 = 0.f;
            if (r == j0 + 2) g2 = 0.f;
            if (r == j0 + 3) g3 = 0.f;
            f4 v = (f4){g0, g1, g2, g3};
            *(f4*)&x[r * LSZ + j0] = v;
            own[k] = v;
        }
    }
    __syncthreads();

    // LDS offsets (f32 elements). Halo strips 4-row-aligned -> contiguous
    // across the wrap; row offsets k*LSZ -> ds immediates.
    const int oT = ((i0 - 4) & (LSZ - 1)) * LSZ + j0;   // top halo strip
    const int oB = ((i0 + 4) & (LSZ - 1)) * LSZ + j0;   // bottom halo strip
    const int oL = i0 * LSZ + ((j0 - 4) & (LSZ - 1));   // left cols
    const int oR = i0 * LSZ + ((j0 + 4) & (LSZ - 1));   // right cols
    const int oO = i0 * LSZ + j0;                       // own rows

    float lsum = 0.f;   // final-layer partial sum (accumulated inline)

    auto do_layer = [&](int l) {
        const float w0 = uni(wsm[l * 5 + 0]);
        const float w1 = uni(wsm[l * 5 + 1]);
        const float w2 = uni(wsm[l * 5 + 2]);
        const float w3 = uni(wsm[l * 5 + 3]);
        const float w4 = uni(wsm[l * 5 + 4]);
        // uniform shift: entering layer l, x = x~ - l; stencil(const) = s*T
        const float sT = -(float)l * (w0 + 4.0f * (w1 + w2 + w3 + w4));

        f4 t[4], bo[4];
#pragma unroll
        for (int k = 0; k < 4; ++k) {
            t[k]  = *(const f4*)&x[oT + k * LSZ];
            bo[k] = *(const f4*)&x[oB + k * LSZ];
        }

        // VV(k): vertical stack rows i0-4+k, k = 0..11
#define VV(k) ((k) < 4 ? t[(k)] : (k) < 8 ? own[(k) - 4] : bo[(k) - 8])

        f4 Lc = *(const f4*)&x[oL];
        f4 Rc = *(const f4*)&x[oR];
#pragma unroll
        for (int m = 0; m < 4; ++m) {
            f4 Ln, Rn;
            if (m < 3) {
                Ln = *(const f4*)&x[oL + (m + 1) * LSZ];
                Rn = *(const f4*)&x[oR + (m + 1) * LSZ];
            }
            const f4 C = own[m];

            // horizontal shifted-pair taps (pk-pair structured)
            f2 h1m = C.xy + C.zw;                      // {C.x+C.z, C.y+C.w}
            f4 h1 = (f4){Lc.w + C.y, h1m.x, h1m.y, C.z + Rc.x};
            f2 h2a = Lc.zw + C.zw;                     // {Lc.z+C.z, Lc.w+C.w}
            f2 h2b = C.xy + Rc.xy;                     // {C.x+Rc.x, C.y+Rc.y}
            f4 h2 = (f4){h2a.x, h2a.y, h2b.x, h2b.y};
            f2 h3m = Lc.zw + Rc.xy;                    // {Lc.z+Rc.x, Lc.w+Rc.y}
            f4 h3 = (f4){Lc.y + C.w, h3m.x, h3m.y, C.x + Rc.z};
            f4 h4 = Lc + Rc;

            // y' = y * log2e (weights pre-scaled); sT folds into the first fma
            f4 y = (w0 * C + sT)
                 + w1 * (h1 + (VV(m + 3) + VV(m + 5)))
                 + w2 * (h2 + (VV(m + 2) + VV(m + 6)))
                 + w3 * (h3 + (VV(m + 1) + VV(m + 7)))
                 + w4 * (h4 + (VV(m + 0) + VV(m + 8)));

            f4 yp = __builtin_elementwise_max(y, (f4)0.0f);
            f4 yn = __builtin_elementwise_min(y, (f4)0.0f);
            f4 e2;
            e2.x = __builtin_amdgcn_exp2f(yn.x);
            e2.y = __builtin_amdgcn_exp2f(yn.y);
            e2.z = __builtin_amdgcn_exp2f(yn.z);
            e2.w = __builtin_amdgcn_exp2f(yn.w);
            f4 r = (yp * LN2 + C) + e2;    // x~_next ("-1" lives in the shift)

            t[m] = r;                      // t[m] dead after this m -> stash

            Lc = Ln; Rc = Rn;
        }
#undef VV
        __syncthreads();                   // all reads of old plane done
#pragma unroll
        for (int m = 0; m < 4; ++m) {
            *(f4*)&x[oO + m * LSZ] = t[m];
            own[m] = t[m];
        }
        if (l == NLAY - 1) {
#pragma unroll
            for (int m = 0; m < 4; ++m) {
                f4 s = own[m];
                lsum += (s.x + s.y) + (s.z + s.w);
            }
        }
        __syncthreads();                   // new plane visible
    };

#pragma unroll 1
    for (int l = 0; l < NLAY; ++l)
        do_layer(l);

    // ---- block reduction of last-layer sums ----
    float local = lsum;
#pragma unroll
    for (int off = 32; off > 0; off >>= 1)
        local += __shfl_down(local, off, 64);

    const int wave = tid >> 6;
    if ((tid & 63) == 0) red[wave] = local;
    __syncthreads();
    if (tid == 0) {
        float s = 0.f;
#pragma unroll
        for (int w = 0; w < 16; ++w) s += red[w];
        ws[bid] = s;
    }
}

__global__ void finish_kernel(const float* __restrict__ ws, float* __restrict__ out) {
    int b = threadIdx.x;
    float s = 0.f;
#pragma unroll
    for (int c = 0; c < NCH; ++c) s += ws[b * NCH + c];
    // x = x~ - 16 after all layers: mean_true = mean(x~) - 16
    out[b] = expf(16.0f - s / (8.0f * 128.0f * 128.0f));
}

extern "C" void kernel_launch(void* const* d_in, const int* in_sizes, int n_in,
                              void* d_out, int out_size, void* d_ws, size_t ws_size,
                              hipStream_t stream) {
    const float* nrm = (const float*)d_in[0];   // (256,128,3) f32
    const float* W   = (const float*)d_in[1];   // (16,8,5) f32
    float* out = (float*)d_out;                 // (256,) f32
    float* ws  = (float*)d_ws;                  // >= 2048 f32 scratch

    plane_kernel<<<dim3(256 * NCH), dim3(1024), 0, stream>>>(nrm, W, ws);
    finish_kernel<<<dim3(1), dim3(256), 0, stream>>>(ws, out);
}

// Round 14
// 292.279 us; speedup vs baseline: 1.2164x; 1.0897x over previous
//
#include <hip/hip_runtime.h>
#include <math.h>

#define LSZ 128
#define NCH 8
#define NLAY 16
#define LOG2E 1.4426950408889634f
#define LN2   0.6931471805599453f

typedef float f4 __attribute__((ext_vector_type(4)));
typedef float f2 __attribute__((ext_vector_type(2)));

// wave-uniform float -> SGPR
__device__ __forceinline__ float uni(float v) {
    return __uint_as_float(__builtin_amdgcn_readfirstlane(__float_as_uint(v)));
}

// unpack 2 bf16 from u32 (bf16->f32 exact)
__device__ __forceinline__ f2 unpk2(unsigned u) {
    f2 r;
    r.x = __uint_as_float(u << 16);
    r.y = __uint_as_float(u & 0xffff0000u);
    return r;
}
struct f8 { f4 a, b; };
// read 8 bf16 (one ds_read_b128) -> two f4
__device__ __forceinline__ f8 ldr8(const unsigned short* p) {
    uint4 w = *(const uint4*)p;
    f2 p0 = unpk2(w.x), p1 = unpk2(w.y), p2 = unpk2(w.z), p3 = unpk2(w.w);
    f8 r;
    r.a = (f4){p0.x, p0.y, p1.x, p1.y};
    r.b = (f4){p2.x, p2.y, p3.x, p3.y};
    return r;
}
// read 4 bf16 (one ds_read_b64) -> f4
__device__ __forceinline__ f4 ldr4(const unsigned short* p) {
    uint2 w = *(const uint2*)p;
    f2 p0 = unpk2(w.x), p1 = unpk2(w.y);
    return (f4){p0.x, p0.y, p1.x, p1.y};
}
// pack 8 f32 -> 8 bf16 RNE (v_cvt_pk_bf16_f32), one ds_write_b128
__device__ __forceinline__ void str8(unsigned short* p, f4 va, f4 vb) {
    unsigned q0, q1, q2, q3;
    asm("v_cvt_pk_bf16_f32 %0, %1, %2" : "=v"(q0) : "v"(va.x), "v"(va.y));
    asm("v_cvt_pk_bf16_f32 %0, %1, %2" : "=v"(q1) : "v"(va.z), "v"(va.w));
    asm("v_cvt_pk_bf16_f32 %0, %1, %2" : "=v"(q2) : "v"(vb.x), "v"(vb.y));
    asm("v_cvt_pk_bf16_f32 %0, %1, %2" : "=v"(q3) : "v"(vb.z), "v"(vb.w));
    *(uint4*)p = make_uint4(q0, q1, q2, q3);
}

// One block per (batch, channel) plane. 512 threads: 32 row-strips x 16
// col-groups, 4 rows x 8 cols per thread. BF16 ping-pong planes (32 KB each,
// ~35 KB/block total -> 2 blocks/CU), single barrier per layer.
// Own rows carried in f32 regs (center taps exact; halo-only bf16 rounding).
// Vertical stencil is accumulated OVER INPUT ROWS: each halo row is read,
// unpacked once, fma'd into the <=4 affected row-accumulators, then dies ->
// small live register set (acc 32 + own 32), no 96-reg window (R12's bug).
// Uniform-shift fold: x = x~ - l; weights pre-scaled by log2e;
// CELU tail = fma(max(y',0), ln2, x~) + exp2(min(y',0)).
__global__ __launch_bounds__(512)
void plane_kernel(const float* __restrict__ nrm,   // (256,128,3)
                  const float* __restrict__ W,     // (16,8,5)
                  float* __restrict__ ws)          // (2048,) per-block sums
{
    __shared__ __align__(16) unsigned short xa[LSZ * LSZ];   // 32768 B
    __shared__ __align__(16) unsigned short xb[LSZ * LSZ];   // 32768 B
    __shared__ float nsm[LSZ * 3];
    __shared__ float wsm[NLAY * 5];
    __shared__ float red[8];

    const int bid = blockIdx.x;
    const int b   = bid >> 3;
    const int c   = bid & 7;
    const int tid = threadIdx.x;

    if (tid < LSZ * 3) nsm[tid] = nrm[b * (LSZ * 3) + tid];
    if (tid < NLAY * 5) {
        int l = tid / 5, d = tid % 5;
        wsm[tid] = W[l * (NCH * 5) + c * 5 + d] * LOG2E;   // pre-scaled
    }
    __syncthreads();

    const int jg = tid & 15;        // col group  -> j0 = 8*jg
    const int is = tid >> 4;        // row strip  -> i0 = 4*is
    const int j0 = jg * 8;
    const int i0 = is * 4;

    f8 own[4];   // this thread's 4 rows x 8 cols (x~ state, f32)

    // ---- init: g[i][j] = dot3(n[i], n[j]), zero diagonal ----
    {
        float njx[8], njy[8], njz[8];
#pragma unroll
        for (int q = 0; q < 8; ++q) {
            njx[q] = nsm[(j0 + q) * 3 + 0];
            njy[q] = nsm[(j0 + q) * 3 + 1];
            njz[q] = nsm[(j0 + q) * 3 + 2];
        }
#pragma unroll
        for (int k = 0; k < 4; ++k) {
            int r = i0 + k;
            float n0 = nsm[r * 3 + 0], n1 = nsm[r * 3 + 1], n2 = nsm[r * 3 + 2];
            float g[8];
#pragma unroll
            for (int q = 0; q < 8; ++q) {
                g[q] = n0 * njx[q] + n1 * njy[q] + n2 * njz[q];
                if (r == j0 + q) g[q] = 0.f;
            }
            own[k].a = (f4){g[0], g[1], g[2], g[3]};
            own[k].b = (f4){g[4], g[5], g[6], g[7]};
            str8(&xa[r * LSZ + j0], own[k].a, own[k].b);
        }
    }
    __syncthreads();

    // LDS offsets (bf16 elements). Halo strips 4-row-aligned -> contiguous
    // across the wrap; row offsets k*LSZ become ds immediates.
    const int oT = ((i0 - 4) & (LSZ - 1)) * LSZ + j0;   // rows i0-4..i0-1
    const int oB = ((i0 + 4) & (LSZ - 1)) * LSZ + j0;   // rows i0+4..i0+7
    const int oL = i0 * LSZ + ((j0 - 4) & (LSZ - 1));   // left 4 cols
    const int oR = i0 * LSZ + ((j0 + 8) & (LSZ - 1));   // right 4 cols
    const int oO = i0 * LSZ + j0;                       // own rows

    float lsum = 0.f;   // final-layer partial sum

    auto do_layer = [&](const unsigned short* src, unsigned short* dst, int l) {
        const float w[5] = { uni(wsm[l * 5 + 0]), uni(wsm[l * 5 + 1]),
                             uni(wsm[l * 5 + 2]), uni(wsm[l * 5 + 3]),
                             uni(wsm[l * 5 + 4]) };
        // uniform shift: entering layer l, x = x~ - l; stencil(const) = s*T
        const float sT = -(float)l * (w[0] + 4.0f * (w[1] + w[2] + w[3] + w[4]));

        f8 acc[4];

        // ---- horizontal taps + center + shift (own rows, L/R halo) ----
#pragma unroll
        for (int m = 0; m < 4; ++m) {
            const f4 A = ldr4(&src[oL + m * LSZ]);   // cols j0-4..j0-1
            const f4 D = ldr4(&src[oR + m * LSZ]);   // cols j0+8..j0+11
            const f4 B = own[m].a, C = own[m].b;

            f4 h1a; { f2 t = B.xy + B.zw; h1a = (f4){A.w + B.y, t.x, t.y, B.z + C.x}; }
            f4 h2a; { f2 u = A.zw + B.zw; f2 v = B.xy + C.xy; h2a = (f4){u.x, u.y, v.x, v.y}; }
            f4 h3a; { f2 t = A.zw + C.xy; h3a = (f4){A.y + B.w, t.x, t.y, B.x + C.z}; }
            f4 h4a = A + C;
            f4 h1b; { f2 t = C.xy + C.zw; h1b = (f4){B.w + C.y, t.x, t.y, C.z + D.x}; }
            f4 h2b; { f2 u = B.zw + C.zw; f2 v = C.xy + D.xy; h2b = (f4){u.x, u.y, v.x, v.y}; }
            f4 h3b; { f2 t = B.zw + D.xy; h3b = (f4){B.y + C.w, t.x, t.y, C.x + D.z}; }
            f4 h4b = B + D;

            acc[m].a = (w[0] * B + sT) + w[1] * h1a + w[2] * h2a + w[3] * h3a + w[4] * h4a;
            acc[m].b = (w[0] * C + sT) + w[1] * h1b + w[2] * h2b + w[3] * h3b + w[4] * h4b;
        }

        // ---- vertical: own rows into other own accumulators ----
#pragma unroll
        for (int k = 0; k < 4; ++k)
#pragma unroll
            for (int m = 0; m < 4; ++m)
                if (m != k) {
                    const float wd = w[(m > k) ? (m - k) : (k - m)];
                    acc[m].a += wd * own[k].a;
                    acc[m].b += wd * own[k].b;
                }

        // ---- vertical: top halo rows (i0-4+k), feed acc[0..k] ----
#pragma unroll
        for (int k = 0; k < 4; ++k) {
            f8 r = ldr8(&src[oT + k * LSZ]);
#pragma unroll
            for (int m = 0; m <= k; ++m) {
                const float wd = w[m - k + 4];
                acc[m].a += wd * r.a;
                acc[m].b += wd * r.b;
            }
        }
        // ---- vertical: bottom halo rows (i0+4+k), feed acc[k..3] ----
#pragma unroll
        for (int k = 0; k < 4; ++k) {
            f8 r = ldr8(&src[oB + k * LSZ]);
#pragma unroll
            for (int m = k; m < 4; ++m) {
                const float wd = w[4 + k - m];
                acc[m].a += wd * r.a;
                acc[m].b += wd * r.b;
            }
        }

        // ---- CELU tail + residual, write, carry ----
#pragma unroll
        for (int m = 0; m < 4; ++m) {
            f4 ya = acc[m].a, yb = acc[m].b;
            f4 ypa = __builtin_elementwise_max(ya, (f4)0.0f);
            f4 yna = __builtin_elementwise_min(ya, (f4)0.0f);
            f4 ypb = __builtin_elementwise_max(yb, (f4)0.0f);
            f4 ynb = __builtin_elementwise_min(yb, (f4)0.0f);
            f4 ea, eb;
            ea.x = __builtin_amdgcn_exp2f(yna.x);
            ea.y = __builtin_amdgcn_exp2f(yna.y);
            ea.z = __builtin_amdgcn_exp2f(yna.z);
            ea.w = __builtin_amdgcn_exp2f(yna.w);
            eb.x = __builtin_amdgcn_exp2f(ynb.x);
            eb.y = __builtin_amdgcn_exp2f(ynb.y);
            eb.z = __builtin_amdgcn_exp2f(ynb.z);
            eb.w = __builtin_amdgcn_exp2f(ynb.w);
            f4 ra = (ypa * LN2 + own[m].a) + ea;   // "-1" lives in the shift
            f4 rb = (ypb * LN2 + own[m].b) + eb;

            str8(&dst[oO + m * LSZ], ra, rb);
            own[m].a = ra; own[m].b = rb;
            if (l == NLAY - 1) {
                f4 s = ra + rb;
                lsum += (s.x + s.y) + (s.z + s.w);
            }
        }
        __syncthreads();                   // single barrier per layer
    };

#pragma unroll 1
    for (int l = 0; l < NLAY; l += 2) {
        do_layer(xa, xb, l);
        do_layer(xb, xa, l + 1);
    }

    // ---- block reduction of last-layer sums ----
    float local = lsum;
#pragma unroll
    for (int off = 32; off > 0; off >>= 1)
        local += __shfl_down(local, off, 64);

    const int wave = tid >> 6;
    if ((tid & 63) == 0) red[wave] = local;
    __syncthreads();
    if (tid == 0) {
        float s = 0.f;
#pragma unroll
        for (int w = 0; w < 8; ++w) s += red[w];
        ws[bid] = s;
    }
}

__global__ void finish_kernel(const float* __restrict__ ws, float* __restrict__ out) {
    int b = threadIdx.x;
    float s = 0.f;
#pragma unroll
    for (int c = 0; c < NCH; ++c) s += ws[b * NCH + c];
    // x = x~ - 16 after all layers: mean_true = mean(x~) - 16
    out[b] = expf(16.0f - s / (8.0f * 128.0f * 128.0f));
}

extern "C" void kernel_launch(void* const* d_in, const int* in_sizes, int n_in,
                              void* d_out, int out_size, void* d_ws, size_t ws_size,
                              hipStream_t stream) {
    const float* nrm = (const float*)d_in[0];   // (256,128,3) f32
    const float* W   = (const float*)d_in[1];   // (16,8,5) f32
    float* out = (float*)d_out;                 // (256,) f32
    float* ws  = (float*)d_ws;                  // >= 2048 f32 scratch

    plane_kernel<<<dim3(256 * NCH), dim3(512), 0, stream>>>(nrm, W, ws);
    finish_kernel<<<dim3(1), dim3(256), 0, stream>>>(ws, out);
}